// Round 2
// baseline (157.346 us; speedup 1.0000x reference)
//
#include <hip/hip_runtime.h>
#include <cstdint>
#include <cstddef>

#define ALPHA_ 0.25f
#define CLAMP_ 1e-4f

static constexpr int BLK = 256;
static constexpr int MAXB = 2048;

// ws layout (bytes) — header words are contiguous so k_init zeroes one range:
//     0 : conf_u[32]  (float bits, atomicMax; all values >= 0 so uint order == float order)
//   128 : vmax_u[32]
//   256 : done counter (1 uint)
//   512 : partial[MAXB] floats
// 16640 : maskbits[N] uints
static constexpr size_t OFF_VMAX = 128;
static constexpr size_t OFF_DONE = 256;
static constexpr size_t OFF_PART = 512;
static constexpr size_t OFF_BITS = 16640;

__global__ void k_init(unsigned int* hdr) {
    int t = threadIdx.x;
    if (t < 65) hdr[t] = 0u;  // conf_u[32] + vmax_u[32] + done
}

__device__ inline unsigned int mask_from_row(const int* __restrict__ boxes, size_t i) {
    const int4* row = (const int4*)(boxes + i * 32);
    unsigned int m = 0u;
#pragma unroll
    for (int q = 0; q < 8; ++q) {
        int4 v = row[q];
        m |= (v.x > 0 ? 1u : 0u) << (4 * q + 0);
        m |= (v.y > 0 ? 1u : 0u) << (4 * q + 1);
        m |= (v.z > 0 ? 1u : 0u) << (4 * q + 2);
        m |= (v.w > 0 ? 1u : 0u) << (4 * q + 3);
    }
    return m;
}

// Reduce 32 register-resident per-thread maxima to 32 global cells.
__device__ inline void reduce_cols_to_global(float* cm, unsigned int* sdst,
                                             unsigned int* gdst, int t) {
    // wave butterfly once per thread (not per row): 32 regs x 6 steps
#pragma unroll
    for (int g = 0; g < 32; ++g) {
#pragma unroll
        for (int off = 32; off > 0; off >>= 1) cm[g] = fmaxf(cm[g], __shfl_xor(cm[g], off));
    }
    if ((t & 63) == 0) {
#pragma unroll
        for (int g = 0; g < 32; ++g) atomicMax(&sdst[g], __float_as_uint(cm[g]));
    }
    __syncthreads();
    if (t < 32) atomicMax(&gdst[t], sdst[t]);
}

// Pass 1: read boxes (128MB) + scores; write bitmask; conf[g] = max masked score per column.
template <bool WRITEBITS>
__global__ void k_pass1(const int* __restrict__ boxes, const float* __restrict__ scores,
                        unsigned int* __restrict__ maskbits, unsigned int* __restrict__ conf_u,
                        int n) {
    __shared__ unsigned int sconf[32];
    const int t = threadIdx.x;
    if (t < 32) sconf[t] = 0u;
    __syncthreads();
    float cmax[32];
#pragma unroll
    for (int g = 0; g < 32; ++g) cmax[g] = 0.0f;
    const size_t stride = (size_t)gridDim.x * blockDim.x;
    for (size_t i = (size_t)blockIdx.x * blockDim.x + t; i < (size_t)n; i += stride) {
        unsigned int m = mask_from_row(boxes, i);
        if (WRITEBITS) maskbits[i] = m;
        float s = scores[i];
#pragma unroll
        for (int g = 0; g < 32; ++g) cmax[g] = fmaxf(cmax[g], ((m >> g) & 1u) ? s : 0.0f);
    }
    reduce_cols_to_global(cmax, sconf, conf_u, t);
}

// Pass 2: vmax[g] = max over masked i of s^conf[g] * iou.
template <bool USEBITS>
__global__ void k_pass2(const unsigned int* __restrict__ maskbits, const int* __restrict__ boxes,
                        const float* __restrict__ scores, const float* __restrict__ ious,
                        const unsigned int* __restrict__ conf_u, unsigned int* __restrict__ vmax_u,
                        int n) {
    __shared__ unsigned int svmax[32];
    __shared__ float scf[32];
    const int t = threadIdx.x;
    if (t < 32) {
        svmax[t] = 0u;
        scf[t] = __uint_as_float(conf_u[t]);
    }
    __syncthreads();
    float cf[32], vm[32];
#pragma unroll
    for (int g = 0; g < 32; ++g) {
        cf[g] = scf[g];
        vm[g] = 0.0f;
    }
    const size_t stride = (size_t)gridDim.x * blockDim.x;
    for (size_t i = (size_t)blockIdx.x * blockDim.x + t; i < (size_t)n; i += stride) {
        unsigned int m = USEBITS ? maskbits[i] : mask_from_row(boxes, i);
        float ls = __logf(scores[i]);
        float iou = ious[i];
#pragma unroll
        for (int g = 0; g < 32; ++g) {
            float v = __expf(cf[g] * ls) * iou;
            vm[g] = fmaxf(vm[g], ((m >> g) & 1u) ? v : 0.0f);
        }
    }
    reduce_cols_to_global(vm, svmax, vmax_u, t);
}

// Pass 3: per-row loss terms, block partials, last-block final reduce.
template <bool USEBITS>
__global__ void k_pass3(const unsigned int* __restrict__ maskbits, const int* __restrict__ boxes,
                        const float* __restrict__ scores, const float* __restrict__ ious,
                        const float* __restrict__ logits, const unsigned int* __restrict__ conf_u,
                        const unsigned int* __restrict__ vmax_u, float* __restrict__ partial,
                        unsigned int* __restrict__ done, const unsigned int* __restrict__ npos_raw,
                        float* __restrict__ out, int n) {
    __shared__ float scf[32], srv[32];
    __shared__ float swsum[BLK / 64];
    __shared__ int slast;
    const int t = threadIdx.x;
    if (t < 32) {
        scf[t] = __uint_as_float(conf_u[t]);
        srv[t] = 1.0f / (__uint_as_float(vmax_u[t]) + CLAMP_);
    }
    __syncthreads();
    float cf[32], rv[32];
#pragma unroll
    for (int g = 0; g < 32; ++g) {
        cf[g] = scf[g];
        rv[g] = srv[g];
    }
    float accpos = 0.0f;  // sum of logp*sum1 + log1mp*sum2  (scaled by -ALPHA later)
    float accneg = 0.0f;  // sum of -log(1-p)*p^2 over empty rows (scaled by 1-ALPHA)
    const size_t stride = (size_t)gridDim.x * blockDim.x;
    for (size_t i = (size_t)blockIdx.x * blockDim.x + t; i < (size_t)n; i += stride) {
        unsigned int m = USEBITS ? maskbits[i] : mask_from_row(boxes, i);
        float x = logits[i];
        float p = 1.0f / (1.0f + __expf(-x));
        p = fminf(fmaxf(p, CLAMP_), 1.0f - CLAMP_);
        float q = 1.0f - p;
        float log1mp = __logf(q);
        if (m == 0u) {
            accneg += -log1mp * p * p;
        } else {
            float logp = __logf(p);
            float ls = __logf(scores[i]);
            float iou = ious[i];
            float sum1 = 0.0f, sum2 = 0.0f;
#pragma unroll
            for (int g = 0; g < 32; ++g) {
                float val = __expf(cf[g] * ls) * iou;
                float w = (val + CLAMP_) * rv[g];
                w = fminf(fmaxf(w, CLAMP_), 1.0f - CLAMP_);
                float a = w * q;
                float b = (1.0f - w) * p;
                bool on = (m >> g) & 1u;
                sum1 += on ? a * a : 0.0f;
                sum2 += on ? b * b : 0.0f;
            }
            accpos += logp * sum1 + log1mp * sum2;
        }
    }
    float tot = (1.0f - ALPHA_) * accneg - ALPHA_ * accpos;
#pragma unroll
    for (int off = 32; off > 0; off >>= 1) tot += __shfl_xor(tot, off);
    if ((t & 63) == 0) swsum[t >> 6] = tot;
    __syncthreads();
    if (t == 0) {
        float s = 0.0f;
#pragma unroll
        for (int w = 0; w < BLK / 64; ++w) s += swsum[w];
        partial[blockIdx.x] = s;
        __threadfence();  // release partials before signaling
        unsigned int old = atomicAdd(done, 1u);
        slast = (old == (unsigned int)gridDim.x - 1u) ? 1 : 0;
    }
    __syncthreads();
    if (slast) {
        float s = 0.0f;
        for (int i = t; i < (int)gridDim.x; i += BLK)
            s += __hip_atomic_load(&partial[i], __ATOMIC_RELAXED, __HIP_MEMORY_SCOPE_AGENT);
#pragma unroll
        for (int off = 32; off > 0; off >>= 1) s += __shfl_xor(s, off);
        if ((t & 63) == 0) swsum[t >> 6] = s;
        __syncthreads();
        if (t == 0) {
            float ttot = 0.0f;
#pragma unroll
            for (int w = 0; w < BLK / 64; ++w) ttot += swsum[w];
            unsigned int v = *npos_raw;
            // num_pos_avg: int32 if exponent bits clear (small int), else float32 bits
            float np = (v & 0x7f800000u) ? __uint_as_float(v) : (float)(int)v;
            out[0] = ttot / np;
        }
    }
}

extern "C" void kernel_launch(void* const* d_in, const int* in_sizes, int n_in,
                              void* d_out, int out_size, void* d_ws, size_t ws_size,
                              hipStream_t stream) {
    const float* logits = (const float*)d_in[0];
    const float* scores = (const float*)d_in[1];
    const float* ious = (const float*)d_in[2];
    const int* boxes = (const int*)d_in[3];
    // d_in[4] = gt_labels (all zeros; scores/IoUMap have a single column) -> ignored
    const unsigned int* npos_raw = (const unsigned int*)d_in[5];
    float* out = (float*)d_out;
    const int n = in_sizes[0];

    unsigned char* ws = (unsigned char*)d_ws;
    unsigned int* conf_u = (unsigned int*)ws;
    unsigned int* vmax_u = (unsigned int*)(ws + OFF_VMAX);
    unsigned int* done = (unsigned int*)(ws + OFF_DONE);
    float* partial = (float*)(ws + OFF_PART);
    unsigned int* maskbits = (unsigned int*)(ws + OFF_BITS);
    const bool usebits = ws_size >= OFF_BITS + (size_t)n * 4u;

    int nbfull = (n + BLK - 1) / BLK;
    int nb = nbfull < MAXB ? nbfull : MAXB;

    k_init<<<dim3(1), dim3(128), 0, stream>>>((unsigned int*)ws);
    if (usebits) {
        k_pass1<true><<<dim3(nb), dim3(BLK), 0, stream>>>(boxes, scores, maskbits, conf_u, n);
        k_pass2<true><<<dim3(nb), dim3(BLK), 0, stream>>>(maskbits, boxes, scores, ious, conf_u,
                                                          vmax_u, n);
        k_pass3<true><<<dim3(nb), dim3(BLK), 0, stream>>>(maskbits, boxes, scores, ious, logits,
                                                          conf_u, vmax_u, partial, done, npos_raw,
                                                          out, n);
    } else {
        k_pass1<false><<<dim3(nb), dim3(BLK), 0, stream>>>(boxes, scores, maskbits, conf_u, n);
        k_pass2<false><<<dim3(nb), dim3(BLK), 0, stream>>>(maskbits, boxes, scores, ious, conf_u,
                                                           vmax_u, n);
        k_pass3<false><<<dim3(nb), dim3(BLK), 0, stream>>>(maskbits, boxes, scores, ious, logits,
                                                           conf_u, vmax_u, partial, done, npos_raw,
                                                           out, n);
    }
}